// Round 6
// baseline (236.271 us; speedup 1.0000x reference)
//
#include <hip/hip_runtime.h>
#include <hip/hip_bf16.h>

#define NN      50000
#define DEG     16
#define FDIM    128
#define BM      64      // rows per block
#define ASTR    296     // attrs LDS row stride (shorts); >=288 for K-pad
#define OSTR    136     // activation LDS row stride (shorts)
// ws layout (shorts): We1t[128][288] | We2t,Wx1t,Wv1t,Wh1t,Wh2t each [128][128]
#define OFF_WE1 0
#define OFF_WE2 36864
#define OFF_WX1 53248
#define OFF_WV1 69632
#define OFF_WH1 86016
#define OFF_WH2 102400
#define WS_SHORTS 118784

typedef short v8s  __attribute__((ext_vector_type(8)));
typedef short v4sh __attribute__((ext_vector_type(4)));
typedef short v2sh __attribute__((ext_vector_type(2)));
typedef float v4f  __attribute__((ext_vector_type(4)));

__device__ __forceinline__ float fast_tanh(float xv) {
    float ax = fabsf(xv);
    float e2 = __expf(2.0f * ax);
    float r  = 1.0f - 2.0f / (e2 + 1.0f);
    return copysignf(r, xv);
}

__device__ __forceinline__ short f2bf(float f) {   // RNE float->bf16
    union { float f; unsigned u; } a; a.f = f;
    unsigned r = a.u + 0x7fffu + ((a.u >> 16) & 1u);
    return (short)(unsigned short)(r >> 16);
}
__device__ __forceinline__ float bf2f(short s) {
    union { unsigned u; float f; } a; a.u = ((unsigned)(unsigned short)s) << 16;
    return a.f;
}

// B-fragments for this wave's 32-col slab: B[ks][nt]
template<int KSTEPS, int KPAD>
__device__ __forceinline__ void load_B(const short* __restrict__ Wt, int l, int w,
                                       v8s B[KSTEPS][2])
{
    const int lm = l & 15, lk = l >> 4;
    const short* b0 = Wt + (size_t)(w * 32 + lm) * KPAD + lk * 8;
#pragma unroll
    for (int ks = 0; ks < KSTEPS; ++ks) {
        B[ks][0] = *(const v8s*)(b0 + ks * 32);
        B[ks][1] = *(const v8s*)(b0 + 16 * KPAD + ks * 32);
    }
}

__device__ __forceinline__ void acc_zero(v4f acc[4][2]) {
    v4f z = {0.f, 0.f, 0.f, 0.f};
#pragma unroll
    for (int mt = 0; mt < 4; ++mt) { acc[mt][0] = z; acc[mt][1] = z; }
}

// acc[4][2] over M=64 (4 tiles) x this wave's 32 cols (2 tiles), K=KSTEPS*32
template<int KSTEPS, int ASTRIDE>
__device__ __forceinline__ void mfma_acc(const short* A, const v8s B[KSTEPS][2],
                                         int l, v4f acc[4][2])
{
    const int lm = l & 15, lk = l >> 4;
    const short* ap = A + lm * ASTRIDE + lk * 8;
#pragma unroll
    for (int ks = 0; ks < KSTEPS; ++ks) {
        v8s a[4];
#pragma unroll
        for (int mt = 0; mt < 4; ++mt)
            a[mt] = *(const v8s*)(ap + mt * 16 * ASTRIDE + ks * 32);
#pragma unroll
        for (int mt = 0; mt < 4; ++mt) {
            acc[mt][0] = __builtin_amdgcn_mfma_f32_16x16x32_bf16(a[mt], B[ks][0], acc[mt][0], 0, 0, 0);
            acc[mt][1] = __builtin_amdgcn_mfma_f32_16x16x32_bf16(a[mt], B[ks][1], acc[mt][1], 0, 0, 0);
        }
    }
}

// +bias, tanh, bf16 -> LDS [64][OSTR]
__device__ __forceinline__ void epi_to_lds(v4f acc[4][2], short* O,
                                           const float* __restrict__ b, int l, int w)
{
    const int rl = (l >> 4) * 4, cl = l & 15;
#pragma unroll
    for (int nt = 0; nt < 2; ++nt) {
        const int col = w * 32 + nt * 16 + cl;
        const float bias = b[col];
#pragma unroll
        for (int mt = 0; mt < 4; ++mt)
#pragma unroll
            for (int r = 0; r < 4; ++r)
                O[(mt * 16 + rl + r) * OSTR + col] = f2bf(fast_tanh(acc[mt][nt][r] + bias));
    }
}

// -------- weight prep: fp32 [K][128] -> bf16 Wt [128][KPAD] in ws --------
__global__ __launch_bounds__(256) void prep_weights(
    const float* __restrict__ We1, const float* __restrict__ We2,
    const float* __restrict__ Wx1, const float* __restrict__ Wv1,
    const float* __restrict__ Wh1, const float* __restrict__ Wh2,
    short* __restrict__ wbuf)
{
    int idx = blockIdx.x * 256 + threadIdx.x;
    if (idx < 128 * 288) {                       // We1t with zero K-pad 273..287
        int c = idx / 288, k = idx % 288;
        wbuf[OFF_WE1 + idx] = (k < 273) ? f2bf(We1[k * FDIM + c]) : (short)0;
        return;
    }
    idx -= 128 * 288;
    if (idx < 5 * 16384) {
        int layer = idx / 16384, r = idx % 16384;
        int c = r / 128, k = r % 128;
        const float* W = (layer == 0) ? We2 : (layer == 1) ? Wx1 :
                         (layer == 2) ? Wv1 : (layer == 3) ? Wh1 : Wh2;
        wbuf[OFF_WE2 + layer * 16384 + c * 128 + k] = f2bf(W[k * FDIM + c]);
    }
}

// -------- edge kernel: 64 edges per block, 4 waves --------
// LDS: bigbuf = attrs (stride ASTR) for layer1, REUSED as buf2 (stride OSTR)
// afterwards (barrier-separated). 55.6 KB -> 2 blocks/CU.
__global__ __launch_bounds__(256, 2) void edge_kernel(
    const float* __restrict__ h, const float* __restrict__ x,
    const float* __restrict__ ea, const int* __restrict__ cols,
    const short* __restrict__ wbuf,
    const float* __restrict__ be1, const float* __restrict__ be2,
    const float* __restrict__ bx1,
    const float* __restrict__ Wx2, const float* __restrict__ bx2,
    float* __restrict__ msum, float* __restrict__ exsum)
{
    __shared__ __align__(16) short bigbuf[BM * ASTR];   // attrs, then buf2
    __shared__ __align__(16) short buf1[BM * OSTR];
    __shared__ float sdiff[BM];

    short* attrs = bigbuf;
    short* buf2  = bigbuf;

    const int tid = threadIdx.x;
    const int e0  = blockIdx.x * BM;
    const int l   = tid & 63, w = tid >> 6;

    // prefetch layer-1 weights (register loads survive barriers)
    v8s B1[9][2];
    load_B<9, 288>(wbuf + OFF_WE1, l, w, B1);

    // ---- stage attrs bf16 = [h_i(128) | h_j(128) | dr | ea(16) | 0-pad->288] ----
    {
        const int el = tid >> 2, q = tid & 3;   // 4 threads per edge row
        int ec = e0 + el; if (ec >= NN) ec = NN - 1;
        const int i = ec >> 4;                  // rows[e] == e/16
        const int j = cols[ec];
        const float4* hi4 = (const float4*)(h + (size_t)i * FDIM) + q * 8;
        const float4* hj4 = (const float4*)(h + (size_t)j * FDIM) + q * 8;
        short* arow = attrs + el * ASTR;
#pragma unroll
        for (int t = 0; t < 8; ++t) {
            float4 v = hi4[t];
            v4sh s = { f2bf(v.x), f2bf(v.y), f2bf(v.z), f2bf(v.w) };
            *(v4sh*)(arow + q * 32 + t * 4) = s;
            float4 u = hj4[t];
            v4sh s2 = { f2bf(u.x), f2bf(u.y), f2bf(u.z), f2bf(u.w) };
            *(v4sh*)(arow + 128 + q * 32 + t * 4) = s2;
        }
        if (q == 0) {
#pragma unroll
            for (int t = 0; t < 16; ++t)
                arow[257 + t] = f2bf(ea[(size_t)ec * 16 + t]);
        }
        if (q == 1) {
            float dx = x[i * 3 + 0] - x[j * 3 + 0];
            float dy = x[i * 3 + 1] - x[j * 3 + 1];
            float dz = x[i * 3 + 2] - x[j * 3 + 2];
            arow[256] = f2bf(dx * dx + dy * dy + dz * dz);
            sdiff[el] = dx + dy + dz;
        }
        if (q == 2) {
#pragma unroll
            for (int t = 0; t < 15; ++t) arow[273 + t] = 0;
        }
    }
    __syncthreads();

    v4f acc[4][2];
    // t1 = tanh(attrs @ We1 + be1)   K=288 (zero-padded)
    acc_zero(acc);
    mfma_acc<9, ASTR>(attrs, B1, l, acc);
    v8s B2[4][2];
    load_B<4, 128>(wbuf + OFF_WE2, l, w, B2);     // prefetch layer 2
    epi_to_lds(acc, buf1, be1, l, w);
    __syncthreads();   // attrs fully consumed -> bigbuf reusable as buf2

    // m = tanh(t1 @ We2 + be2)
    acc_zero(acc);
    mfma_acc<4, OSTR>(buf1, B2, l, acc);
    v8s B3[4][2];
    load_B<4, 128>(wbuf + OFF_WX1, l, w, B3);     // prefetch layer 3
    epi_to_lds(acc, buf2, be2, l, w);
    __syncthreads();

    // msum[e] = sum_f m[e][f]   (wave w owns rows [w*16, w*16+16))
#pragma unroll
    for (int e = 0; e < 16; ++e) {
        int row = w * 16 + e;
        v2sh p = *(const v2sh*)(buf2 + row * OSTR + 2 * l);
        float s = bf2f(p.x) + bf2f(p.y);
#pragma unroll
        for (int m = 32; m >= 1; m >>= 1) s += __shfl_xor(s, m, 64);
        if (l == 0) {
            int eg = e0 + row;
            if (eg < NN) msum[eg] = s;
        }
    }

    // t2 = tanh(m @ Wx1 + bx1)
    acc_zero(acc);
    mfma_acc<4, OSTR>(buf2, B3, l, acc);
    epi_to_lds(acc, buf1, bx1, l, w);
    __syncthreads();

    // phi = tanh(t2 . Wx2 + bx2); exsum = phi * (dx+dy+dz)
    {
        const float wx0 = Wx2[2 * l], wx1 = Wx2[2 * l + 1];
        const float bxx = bx2[0];
#pragma unroll
        for (int e = 0; e < 16; ++e) {
            int row = w * 16 + e;
            v2sh p = *(const v2sh*)(buf1 + row * OSTR + 2 * l);
            float s = bf2f(p.x) * wx0 + bf2f(p.y) * wx1;
#pragma unroll
            for (int m = 32; m >= 1; m >>= 1) s += __shfl_xor(s, m, 64);
            if (l == 0) {
                int eg = e0 + row;
                if (eg < NN) exsum[eg] = fast_tanh(s + bxx) * sdiff[row];
            }
        }
    }
}

// -------- node kernel: 64 nodes per block, 4 waves --------
__global__ __launch_bounds__(256, 3) void node_kernel(
    const float* __restrict__ h, const float* __restrict__ x,
    const float* __restrict__ vel, const int* __restrict__ cols,
    const short* __restrict__ wbuf,
    const float* __restrict__ bv1, const float* __restrict__ Wv2,
    const float* __restrict__ bv2,
    const float* __restrict__ bh1, const float* __restrict__ Wh1f,
    const float* __restrict__ bh2,
    const float* __restrict__ msum, const float* __restrict__ exsum,
    float* __restrict__ out_h, float* __restrict__ out_x, float* __restrict__ out_v)
{
    __shared__ __align__(16) short hn[BM * OSTR];
    __shared__ __align__(16) short buf1[BM * OSTR];
    __shared__ float mi[BM], media[BM], phiv[BM];

    const int tid = threadIdx.x;
    const int n0  = blockIdx.x * BM;
    const int l   = tid & 63, w = tid >> 6;

    // prefetch layer weights for Wv1 and Wh1
    v8s B1[4][2], B2[4][2];
    load_B<4, 128>(wbuf + OFF_WV1, l, w, B1);
    load_B<4, 128>(wbuf + OFF_WH1, l, w, B2);

    // stage h rows -> bf16 LDS
    {
        const int el = tid >> 2, q = tid & 3;
        int nc = n0 + el; if (nc >= NN) nc = NN - 1;
        const float4* hr = (const float4*)(h + (size_t)nc * FDIM) + q * 8;
        short* arow = hn + el * OSTR;
#pragma unroll
        for (int t = 0; t < 8; ++t) {
            float4 v = hr[t];
            v4sh s = { f2bf(v.x), f2bf(v.y), f2bf(v.z), f2bf(v.w) };
            *(v4sh*)(arow + q * 32 + t * 4) = s;
        }
    }
    // gather m_i and media (node i's edges are [16i,16i+16))
    {
#pragma unroll
        for (int r = 0; r < 4; ++r) {
            int idx = tid + r * 256;           // 0..1023 = 64 nodes x 16
            int nl = idx >> 4, kk = idx & 15;
            int nc = n0 + nl; if (nc >= NN) nc = NN - 1;
            int c = cols[(size_t)nc * DEG + kk];
            float ms = msum[c];
            float ex = exsum[c];
#pragma unroll
            for (int m = 8; m >= 1; m >>= 1) {
                ms += __shfl_xor(ms, m, 64);
                ex += __shfl_xor(ex, m, 64);
            }
            if (kk == 0) { mi[nl] = ms; media[nl] = ex * (1.0f / 16.0f); }
        }
    }
    __syncthreads();

    v4f acc[4][2];
    // tv = tanh(h @ Wv1 + bv1)
    acc_zero(acc);
    mfma_acc<4, OSTR>(hn, B1, l, acc);
    v8s B3[4][2];
    load_B<4, 128>(wbuf + OFF_WH2, l, w, B3);     // prefetch final layer
    epi_to_lds(acc, buf1, bv1, l, w);
    __syncthreads();

    // phi_v = tv . Wv2 + bv2
    {
        const float wv0 = Wv2[2 * l], wv1 = Wv2[2 * l + 1];
        const float bvv = bv2[0];
#pragma unroll
        for (int e = 0; e < 16; ++e) {
            int row = w * 16 + e;
            v2sh p = *(const v2sh*)(buf1 + row * OSTR + 2 * l);
            float s = bf2f(p.x) * wv0 + bf2f(p.y) * wv1;
#pragma unroll
            for (int m = 32; m >= 1; m >>= 1) s += __shfl_xor(s, m, 64);
            if (l == 0) phiv[row] = s + bvv;
        }
    }
    __syncthreads();

    // th = tanh([h|m_i] @ Wh1 + bh1): MFMA over K=128 + mi*Wh1[128][:] in epilogue
    acc_zero(acc);
    mfma_acc<4, OSTR>(hn, B2, l, acc);
    {
        const int rl = (l >> 4) * 4, cl = l & 15;
        const float* w128 = Wh1f + (size_t)FDIM * FDIM;
#pragma unroll
        for (int nt = 0; nt < 2; ++nt) {
            const int col = w * 32 + nt * 16 + cl;
            const float bias = bh1[col], wr = w128[col];
#pragma unroll
            for (int mt = 0; mt < 4; ++mt)
#pragma unroll
                for (int r = 0; r < 4; ++r) {
                    int row = mt * 16 + rl + r;
                    buf1[row * OSTR + col] =
                        f2bf(fast_tanh(acc[mt][nt][r] + bias + mi[row] * wr));
                }
        }
    }
    __syncthreads();

    // h_new = th @ Wh2 + bh2 -> global fp32
    acc_zero(acc);
    mfma_acc<4, OSTR>(buf1, B3, l, acc);
    {
        const int rl = (l >> 4) * 4, cl = l & 15;
#pragma unroll
        for (int nt = 0; nt < 2; ++nt) {
            const int col = w * 32 + nt * 16 + cl;
            const float bias = bh2[col];
#pragma unroll
            for (int mt = 0; mt < 4; ++mt)
#pragma unroll
                for (int r = 0; r < 4; ++r) {
                    int rg = n0 + mt * 16 + rl + r;
                    if (rg < NN) out_h[(size_t)rg * FDIM + col] = acc[mt][nt][r] + bias;
                }
        }
    }

    // vel_new / x_new
    if (tid < BM * 3) {
        int nl = tid / 3, d = tid % 3;
        int n = n0 + nl;
        if (n < NN) {
            float vv = vel[(size_t)n * 3 + d] * phiv[nl] + media[nl];
            out_v[(size_t)n * 3 + d] = vv;
            out_x[(size_t)n * 3 + d] = x[(size_t)n * 3 + d] + vv;
        }
    }
}

extern "C" void kernel_launch(void* const* d_in, const int* in_sizes, int n_in,
                              void* d_out, int out_size, void* d_ws, size_t ws_size,
                              hipStream_t stream)
{
    (void)in_sizes; (void)n_in; (void)out_size; (void)ws_size;
    const float* h    = (const float*)d_in[0];
    const float* x    = (const float*)d_in[1];
    const float* vel  = (const float*)d_in[2];
    const float* ea   = (const float*)d_in[3];
    const int*   cols = (const int*)d_in[5];
    const float* We1 = (const float*)d_in[6];  const float* be1 = (const float*)d_in[7];
    const float* We2 = (const float*)d_in[8];  const float* be2 = (const float*)d_in[9];
    const float* Wx1 = (const float*)d_in[10]; const float* bx1 = (const float*)d_in[11];
    const float* Wx2 = (const float*)d_in[12]; const float* bx2 = (const float*)d_in[13];
    const float* Wh1 = (const float*)d_in[14]; const float* bh1 = (const float*)d_in[15];
    const float* Wh2 = (const float*)d_in[16]; const float* bh2 = (const float*)d_in[17];
    const float* Wv1 = (const float*)d_in[18]; const float* bv1 = (const float*)d_in[19];
    const float* Wv2 = (const float*)d_in[20]; const float* bv2 = (const float*)d_in[21];

    short* wbuf  = (short*)d_ws;
    float* msum  = (float*)((char*)d_ws + WS_SHORTS * sizeof(short));
    float* exsum = msum + NN;
    float* out_h = (float*)d_out;
    float* out_x = out_h + (size_t)NN * FDIM;
    float* out_v = out_x + (size_t)NN * 3;

    dim3 block(256);
    prep_weights<<<dim3((WS_SHORTS + 255) / 256), block, 0, stream>>>(
        We1, We2, Wx1, Wv1, Wh1, Wh2, wbuf);
    dim3 grid((NN + BM - 1) / BM);
    edge_kernel<<<grid, block, 0, stream>>>(h, x, ea, cols, wbuf,
                                            be1, be2, bx1, Wx2, bx2, msum, exsum);
    node_kernel<<<grid, block, 0, stream>>>(h, x, vel, cols, wbuf,
                                            bv1, Wv2, bv2, bh1, Wh1, bh2,
                                            msum, exsum, out_h, out_x, out_v);
}

// Round 7
// 218.398 us; speedup vs baseline: 1.0818x; 1.0818x over previous
//
#include <hip/hip_runtime.h>
#include <hip/hip_bf16.h>

#define NN      50000
#define DEG     16
#define FDIM    128
#define BM      32      // rows per block
#define ASTR    296     // attrs LDS row stride (shorts); >=288 for K-pad
#define OSTR    136     // activation LDS row stride (shorts)
// ws layout (shorts): We1t[128][288] | We2t,Wx1t,Wv1t,Wh1t,Wh2t each [128][128]
#define OFF_WE1 0
#define OFF_WE2 36864
#define OFF_WX1 53248
#define OFF_WV1 69632
#define OFF_WH1 86016
#define OFF_WH2 102400
#define WS_SHORTS 118784

typedef short v8s  __attribute__((ext_vector_type(8)));
typedef short v4sh __attribute__((ext_vector_type(4)));
typedef float v4f  __attribute__((ext_vector_type(4)));

__device__ __forceinline__ float fast_tanh(float xv) {
    float ax = fabsf(xv);
    float e2 = __expf(2.0f * ax);
    float r  = 1.0f - 2.0f / (e2 + 1.0f);
    return copysignf(r, xv);
}

__device__ __forceinline__ short f2bf(float f) {   // RNE float->bf16
    union { float f; unsigned u; } a; a.f = f;
    unsigned r = a.u + 0x7fffu + ((a.u >> 16) & 1u);
    return (short)(unsigned short)(r >> 16);
}

// B-fragments for this wave's 32-col slab (held in registers)
template<int KSTEPS, int KPAD>
__device__ __forceinline__ void load_B(const short* __restrict__ Wt, int l, int w,
                                       v8s B[KSTEPS][2])
{
    const int lm = l & 15, lk = l >> 4;
    const short* b0 = Wt + (size_t)(w * 32 + lm) * KPAD + lk * 8;
#pragma unroll
    for (int ks = 0; ks < KSTEPS; ++ks) {
        B[ks][0] = *(const v8s*)(b0 + ks * 32);
        B[ks][1] = *(const v8s*)(b0 + 16 * KPAD + ks * 32);
    }
}

__device__ __forceinline__ void acc_zero(v4f acc[2][2]) {
    v4f z = {0.f, 0.f, 0.f, 0.f};
    acc[0][0] = z; acc[0][1] = z; acc[1][0] = z; acc[1][1] = z;
}

// M=32 (2 m-tiles) x wave's 32 cols (2 n-tiles), B from registers
template<int KSTEPS, int ASTRIDE>
__device__ __forceinline__ void mfma_regB(const short* A, const v8s B[KSTEPS][2],
                                          int l, v4f acc[2][2])
{
    const int lm = l & 15, lk = l >> 4;
    const short* ap = A + lm * ASTRIDE + lk * 8;
#pragma unroll
    for (int ks = 0; ks < KSTEPS; ++ks) {
        v8s a0 = *(const v8s*)(ap + ks * 32);
        v8s a1 = *(const v8s*)(ap + 16 * ASTRIDE + ks * 32);
        acc[0][0] = __builtin_amdgcn_mfma_f32_16x16x32_bf16(a0, B[ks][0], acc[0][0], 0, 0, 0);
        acc[1][0] = __builtin_amdgcn_mfma_f32_16x16x32_bf16(a1, B[ks][0], acc[1][0], 0, 0, 0);
        acc[0][1] = __builtin_amdgcn_mfma_f32_16x16x32_bf16(a0, B[ks][1], acc[0][1], 0, 0, 0);
        acc[1][1] = __builtin_amdgcn_mfma_f32_16x16x32_bf16(a1, B[ks][1], acc[1][1], 0, 0, 0);
    }
}

// same but B loaded inline from global (KPAD=128) — keeps VGPR low
template<int KSTEPS, int ASTRIDE>
__device__ __forceinline__ void mfma_ldB(const short* A, const short* __restrict__ Wt,
                                         int l, int w, v4f acc[2][2])
{
    const int lm = l & 15, lk = l >> 4;
    const short* ap = A + lm * ASTRIDE + lk * 8;
    const short* b0 = Wt + (size_t)(w * 32 + lm) * 128 + lk * 8;
#pragma unroll
    for (int ks = 0; ks < KSTEPS; ++ks) {
        v8s a0 = *(const v8s*)(ap + ks * 32);
        v8s a1 = *(const v8s*)(ap + 16 * ASTRIDE + ks * 32);
        v8s bb0 = *(const v8s*)(b0 + ks * 32);
        v8s bb1 = *(const v8s*)(b0 + 16 * 128 + ks * 32);
        acc[0][0] = __builtin_amdgcn_mfma_f32_16x16x32_bf16(a0, bb0, acc[0][0], 0, 0, 0);
        acc[1][0] = __builtin_amdgcn_mfma_f32_16x16x32_bf16(a1, bb0, acc[1][0], 0, 0, 0);
        acc[0][1] = __builtin_amdgcn_mfma_f32_16x16x32_bf16(a0, bb1, acc[0][1], 0, 0, 0);
        acc[1][1] = __builtin_amdgcn_mfma_f32_16x16x32_bf16(a1, bb1, acc[1][1], 0, 0, 0);
    }
}

// +bias, tanh, bf16 -> LDS [32][OSTR]
__device__ __forceinline__ void epi_tanh_lds(v4f acc[2][2], short* O,
                                             const float* __restrict__ b, int l, int w)
{
    const int rl = (l >> 4) * 4, cl = l & 15;
#pragma unroll
    for (int nt = 0; nt < 2; ++nt) {
        const int col = w * 32 + nt * 16 + cl;
        const float bias = b[col];
#pragma unroll
        for (int mt = 0; mt < 2; ++mt)
#pragma unroll
            for (int r = 0; r < 4; ++r)
                O[(mt * 16 + rl + r) * OSTR + col] = f2bf(fast_tanh(acc[mt][nt][r] + bias));
    }
}

// 16-lane-group row reduce of per-lane partials -> part_out[w][row]
__device__ __forceinline__ void row_part_store(float part[2][4], float* part_out,
                                               int l, int w)
{
    const int rl = (l >> 4) * 4;
#pragma unroll
    for (int mt = 0; mt < 2; ++mt)
#pragma unroll
        for (int r = 0; r < 4; ++r) {
            float s = part[mt][r];
            s += __shfl_xor(s, 1, 64);
            s += __shfl_xor(s, 2, 64);
            s += __shfl_xor(s, 4, 64);
            s += __shfl_xor(s, 8, 64);
            if ((l & 15) == 0) part_out[w * BM + mt * 16 + rl + r] = s;
        }
}

// -------- weight prep: fp32 [K][128] -> bf16 Wt [128][KPAD] in ws --------
__global__ __launch_bounds__(256) void prep_weights(
    const float* __restrict__ We1, const float* __restrict__ We2,
    const float* __restrict__ Wx1, const float* __restrict__ Wv1,
    const float* __restrict__ Wh1, const float* __restrict__ Wh2,
    short* __restrict__ wbuf)
{
    int idx = blockIdx.x * 256 + threadIdx.x;
    if (idx < 128 * 288) {                       // We1t with zero K-pad 273..287
        int c = idx / 288, k = idx % 288;
        wbuf[OFF_WE1 + idx] = (k < 273) ? f2bf(We1[k * FDIM + c]) : (short)0;
        return;
    }
    idx -= 128 * 288;
    if (idx < 5 * 16384) {
        int layer = idx / 16384, r = idx % 16384;
        int c = r / 128, k = r % 128;
        const float* W = (layer == 0) ? We2 : (layer == 1) ? Wx1 :
                         (layer == 2) ? Wv1 : (layer == 3) ? Wh1 : Wh2;
        wbuf[OFF_WE2 + layer * 16384 + c * 128 + k] = f2bf(W[k * FDIM + c]);
    }
}

// -------- edge kernel: 32 edges per block, 4 waves, each wave 32 cols --------
// LDS 28.8 KB -> 5 blocks/CU. bigbuf = attrs (ASTR) for L1, reused as buf2
// (OSTR) afterwards — barrier-separated.
__global__ __launch_bounds__(256) void edge_kernel(
    const float* __restrict__ h, const float* __restrict__ x,
    const float* __restrict__ ea, const int* __restrict__ cols,
    const short* __restrict__ wbuf,
    const float* __restrict__ be1, const float* __restrict__ be2,
    const float* __restrict__ bx1,
    const float* __restrict__ Wx2, const float* __restrict__ bx2,
    float* __restrict__ msum, float* __restrict__ exsum)
{
    __shared__ __align__(16) short bigbuf[BM * ASTR];   // attrs, then buf2
    __shared__ __align__(16) short buf1[BM * OSTR];
    __shared__ float sdiff[BM];
    __shared__ float part_m[4 * BM];
    __shared__ float part_p[4 * BM];

    short* attrs = bigbuf;
    short* buf2  = bigbuf;

    const int tid = threadIdx.x;
    const int e0  = blockIdx.x * BM;
    const int l   = tid & 63, w = tid >> 6;

    // prefetch layer-1 B fragments (registers survive barriers)
    v8s B1[9][2];
    load_B<9, 288>(wbuf + OFF_WE1, l, w, B1);

    // ---- stage attrs bf16 = [h_i(128) | h_j(128) | dr | ea(16) | pad->288] ----
    {
        const int el = tid >> 3, q = tid & 7;   // 8 threads per edge row
        int ec = e0 + el; if (ec >= NN) ec = NN - 1;
        const int i = ec >> 4;                  // rows[e] == e/16
        const int j = cols[ec];
        const float4* hi4 = (const float4*)(h + (size_t)i * FDIM);
        const float4* hj4 = (const float4*)(h + (size_t)j * FDIM);
        short* arow = attrs + el * ASTR;
#pragma unroll
        for (int t = 0; t < 4; ++t) {
            float4 v = hi4[q * 4 + t];
            v4sh s = { f2bf(v.x), f2bf(v.y), f2bf(v.z), f2bf(v.w) };
            *(v4sh*)(arow + q * 16 + t * 4) = s;
            float4 u = hj4[q * 4 + t];
            v4sh s2 = { f2bf(u.x), f2bf(u.y), f2bf(u.z), f2bf(u.w) };
            *(v4sh*)(arow + 128 + q * 16 + t * 4) = s2;
        }
        if (q < 2) {
#pragma unroll
            for (int t = 0; t < 8; ++t)
                arow[257 + q * 8 + t] = f2bf(ea[(size_t)ec * 16 + q * 8 + t]);
        }
        if (q == 2) {
            float dx = x[i * 3 + 0] - x[j * 3 + 0];
            float dy = x[i * 3 + 1] - x[j * 3 + 1];
            float dz = x[i * 3 + 2] - x[j * 3 + 2];
            arow[256] = f2bf(dx * dx + dy * dy + dz * dz);
            sdiff[el] = dx + dy + dz;
        }
        if (q == 3) {
#pragma unroll
            for (int t = 0; t < 15; ++t) arow[273 + t] = 0;
        }
    }
    __syncthreads();

    v4f acc[2][2];
    // L1: t1 = tanh(attrs @ We1 + be1)
    acc_zero(acc);
    mfma_regB<9, ASTR>(attrs, B1, l, acc);
    epi_tanh_lds(acc, buf1, be1, l, w);
    __syncthreads();   // attrs fully consumed -> bigbuf reusable as buf2

    // L2: m = tanh(t1 @ We2 + be2) -> buf2; msum row-partials from registers
    acc_zero(acc);
    mfma_ldB<4, OSTR>(buf1, wbuf + OFF_WE2, l, w, acc);
    {
        const int rl = (l >> 4) * 4, cl = l & 15;
        float part[2][4] = {{0,0,0,0},{0,0,0,0}};
#pragma unroll
        for (int nt = 0; nt < 2; ++nt) {
            const int col = w * 32 + nt * 16 + cl;
            const float bias = be2[col];
#pragma unroll
            for (int mt = 0; mt < 2; ++mt)
#pragma unroll
                for (int r = 0; r < 4; ++r) {
                    float t = fast_tanh(acc[mt][nt][r] + bias);
                    buf2[(mt * 16 + rl + r) * OSTR + col] = f2bf(t);
                    part[mt][r] += t;
                }
        }
        row_part_store(part, part_m, l, w);
    }
    __syncthreads();

    // L3: t2 = tanh(m @ Wx1 + bx1); phi partial = t2 . Wx2 (never touches LDS)
    acc_zero(acc);
    mfma_ldB<4, OSTR>(buf2, wbuf + OFF_WX1, l, w, acc);
    {
        const int cl = l & 15;
        float part[2][4] = {{0,0,0,0},{0,0,0,0}};
#pragma unroll
        for (int nt = 0; nt < 2; ++nt) {
            const int col = w * 32 + nt * 16 + cl;
            const float bias = bx1[col];
            const float wx = Wx2[col];
#pragma unroll
            for (int mt = 0; mt < 2; ++mt)
#pragma unroll
                for (int r = 0; r < 4; ++r)
                    part[mt][r] += fast_tanh(acc[mt][nt][r] + bias) * wx;
        }
        row_part_store(part, part_p, l, w);
    }
    __syncthreads();

    // finalize: 64 threads
    if (tid < BM) {
        int row = tid, eg = e0 + row;
        float ms = part_m[row] + part_m[BM + row] + part_m[2 * BM + row] + part_m[3 * BM + row];
        if (eg < NN) msum[eg] = ms;
    } else if (tid < 2 * BM) {
        int row = tid - BM, eg = e0 + row;
        float ps = part_p[row] + part_p[BM + row] + part_p[2 * BM + row] + part_p[3 * BM + row];
        if (eg < NN) exsum[eg] = fast_tanh(ps + bx2[0]) * sdiff[row];
    }
}

// -------- node kernel: 32 nodes per block, 4 waves, 2 barriers total --------
__global__ __launch_bounds__(256) void node_kernel(
    const float* __restrict__ h, const float* __restrict__ x,
    const float* __restrict__ vel, const int* __restrict__ cols,
    const short* __restrict__ wbuf,
    const float* __restrict__ bv1, const float* __restrict__ Wv2,
    const float* __restrict__ bv2,
    const float* __restrict__ bh1, const float* __restrict__ Wh1f,
    const float* __restrict__ bh2,
    const float* __restrict__ msum, const float* __restrict__ exsum,
    float* __restrict__ out_h, float* __restrict__ out_x, float* __restrict__ out_v)
{
    __shared__ __align__(16) short hn[BM * OSTR];
    __shared__ __align__(16) short buf1[BM * OSTR];
    __shared__ float mi[BM], media[BM];
    __shared__ float part_v[4 * BM];

    const int tid = threadIdx.x;
    const int n0  = blockIdx.x * BM;
    const int l   = tid & 63, w = tid >> 6;

    // stage h rows -> bf16 LDS
    {
        const int el = tid >> 3, q = tid & 7;
        int nc = n0 + el; if (nc >= NN) nc = NN - 1;
        const float4* hr = (const float4*)(h + (size_t)nc * FDIM);
        short* arow = hn + el * OSTR;
#pragma unroll
        for (int t = 0; t < 4; ++t) {
            float4 v = hr[q * 4 + t];
            v4sh s = { f2bf(v.x), f2bf(v.y), f2bf(v.z), f2bf(v.w) };
            *(v4sh*)(arow + q * 16 + t * 4) = s;
        }
    }
    // gather m_i and media (node i's edges are [16i,16i+16))
    {
#pragma unroll
        for (int r = 0; r < 2; ++r) {
            int idx = tid + r * 256;           // 0..511 = 32 nodes x 16
            int nl = idx >> 4, kk = idx & 15;
            int nc = n0 + nl; if (nc >= NN) nc = NN - 1;
            int c = cols[(size_t)nc * DEG + kk];
            float ms = msum[c];
            float ex = exsum[c];
#pragma unroll
            for (int m = 8; m >= 1; m >>= 1) {
                ms += __shfl_xor(ms, m, 64);
                ex += __shfl_xor(ex, m, 64);
            }
            if (kk == 0) { mi[nl] = ms; media[nl] = ex * (1.0f / 16.0f); }
        }
    }
    __syncthreads();

    v4f acc[2][2];
    // Lv1: tv = tanh(h @ Wv1 + bv1); phi_v partial = tv . Wv2 (registers only)
    acc_zero(acc);
    mfma_ldB<4, OSTR>(hn, wbuf + OFF_WV1, l, w, acc);
    {
        const int cl = l & 15;
        float part[2][4] = {{0,0,0,0},{0,0,0,0}};
#pragma unroll
        for (int nt = 0; nt < 2; ++nt) {
            const int col = w * 32 + nt * 16 + cl;
            const float bias = bv1[col];
            const float wv = Wv2[col];
#pragma unroll
            for (int mt = 0; mt < 2; ++mt)
#pragma unroll
                for (int r = 0; r < 4; ++r)
                    part[mt][r] += fast_tanh(acc[mt][nt][r] + bias) * wv;
        }
        row_part_store(part, part_v, l, w);
    }
    // Lh1 (same phase — disjoint LDS): th = tanh([h|m_i] @ Wh1 + bh1) -> buf1
    acc_zero(acc);
    mfma_ldB<4, OSTR>(hn, wbuf + OFF_WH1, l, w, acc);
    {
        const int rl = (l >> 4) * 4, cl = l & 15;
        const float* w128 = Wh1f + (size_t)FDIM * FDIM;
#pragma unroll
        for (int nt = 0; nt < 2; ++nt) {
            const int col = w * 32 + nt * 16 + cl;
            const float bias = bh1[col], wr = w128[col];
#pragma unroll
            for (int mt = 0; mt < 2; ++mt)
#pragma unroll
                for (int r = 0; r < 4; ++r) {
                    int row = mt * 16 + rl + r;
                    buf1[row * OSTR + col] =
                        f2bf(fast_tanh(acc[mt][nt][r] + bias + mi[row] * wr));
                }
        }
    }
    __syncthreads();

    // Lh2: h_new = th @ Wh2 + bh2 -> global fp32
    acc_zero(acc);
    mfma_ldB<4, OSTR>(buf1, wbuf + OFF_WH2, l, w, acc);
    {
        const int rl = (l >> 4) * 4, cl = l & 15;
#pragma unroll
        for (int nt = 0; nt < 2; ++nt) {
            const int col = w * 32 + nt * 16 + cl;
            const float bias = bh2[col];
#pragma unroll
            for (int mt = 0; mt < 2; ++mt)
#pragma unroll
                for (int r = 0; r < 4; ++r) {
                    int rg = n0 + mt * 16 + rl + r;
                    if (rg < NN) out_h[(size_t)rg * FDIM + col] = acc[mt][nt][r] + bias;
                }
        }
    }

    // vel_new / x_new: read the 4 phi_v partials directly
    if (tid < BM * 3) {
        int nl = tid / 3, d = tid % 3;
        int n = n0 + nl;
        if (n < NN) {
            float pv = bv2[0] + part_v[nl] + part_v[BM + nl]
                     + part_v[2 * BM + nl] + part_v[3 * BM + nl];
            float vv = vel[(size_t)n * 3 + d] * pv + media[nl];
            out_v[(size_t)n * 3 + d] = vv;
            out_x[(size_t)n * 3 + d] = x[(size_t)n * 3 + d] + vv;
        }
    }
}

extern "C" void kernel_launch(void* const* d_in, const int* in_sizes, int n_in,
                              void* d_out, int out_size, void* d_ws, size_t ws_size,
                              hipStream_t stream)
{
    (void)in_sizes; (void)n_in; (void)out_size; (void)ws_size;
    const float* h    = (const float*)d_in[0];
    const float* x    = (const float*)d_in[1];
    const float* vel  = (const float*)d_in[2];
    const float* ea   = (const float*)d_in[3];
    const int*   cols = (const int*)d_in[5];
    const float* We1 = (const float*)d_in[6];  const float* be1 = (const float*)d_in[7];
    const float* We2 = (const float*)d_in[8];  const float* be2 = (const float*)d_in[9];
    const float* Wx1 = (const float*)d_in[10]; const float* bx1 = (const float*)d_in[11];
    const float* Wx2 = (const float*)d_in[12]; const float* bx2 = (const float*)d_in[13];
    const float* Wh1 = (const float*)d_in[14]; const float* bh1 = (const float*)d_in[15];
    const float* Wh2 = (const float*)d_in[16]; const float* bh2 = (const float*)d_in[17];
    const float* Wv1 = (const float*)d_in[18]; const float* bv1 = (const float*)d_in[19];
    const float* Wv2 = (const float*)d_in[20]; const float* bv2 = (const float*)d_in[21];

    short* wbuf  = (short*)d_ws;
    float* msum  = (float*)((char*)d_ws + WS_SHORTS * sizeof(short));
    float* exsum = msum + NN;
    float* out_h = (float*)d_out;
    float* out_x = out_h + (size_t)NN * FDIM;
    float* out_v = out_x + (size_t)NN * 3;

    dim3 block(256);
    prep_weights<<<dim3((WS_SHORTS + 255) / 256), block, 0, stream>>>(
        We1, We2, Wx1, Wv1, Wh1, Wh2, wbuf);
    dim3 grid((NN + BM - 1) / BM);
    edge_kernel<<<grid, block, 0, stream>>>(h, x, ea, cols, wbuf,
                                            be1, be2, bx1, Wx2, bx2, msum, exsum);
    node_kernel<<<grid, block, 0, stream>>>(h, x, vel, cols, wbuf,
                                            bv1, Wv2, bv2, bh1, Wh1, bh2,
                                            msum, exsum, out_h, out_x, out_v);
}